// Round 11
// baseline (270.263 us; speedup 1.0000x reference)
//
#include <hip/hip_runtime.h>
#include <math.h>

#define N_  4
#define H_  96
#define W_  96
#define HW  9216          // H*W
#define NHW 36864         // N*H*W
#define O_  128
#define PW  98            // padded width/height
#define PHW 9604          // PW*PW

typedef unsigned short ushort_t;
typedef __attribute__((ext_vector_type(8))) short bf16x8;
typedef __attribute__((ext_vector_type(4))) float f32x4;
typedef __attribute__((ext_vector_type(8))) unsigned short u16x8;

__device__ __forceinline__ float bf2f(ushort_t u) {
  return __uint_as_float(((unsigned int)u) << 16);
}
__device__ __forceinline__ ushort_t f2bf(float f) {
  unsigned int u = __float_as_uint(f);
  u += 0x7fffu + ((u >> 16) & 1u);           // RNE
  return (ushort_t)(u >> 16);
}

// ---------------------------------------------------------------------------
// NCHW fp32 -> padded NHWC bf16 ([n][98][98][C], interior only; borders memset)
__global__ __launch_bounds__(256) void to_nhwc_pad_kernel(const float* __restrict__ x,
                                                          ushort_t* __restrict__ xp, int C) {
  __shared__ ushort_t L[32][33];
  int ctiles = C >> 5;
  int b = blockIdx.x;
  int ct = b % ctiles;
  int hwt = (b / ctiles) % (HW / 32);
  int n = b / (ctiles * (HW / 32));
  int tx = threadIdx.x & 31, ty = threadIdx.x >> 5;
#pragma unroll
  for (int i = 0; i < 4; ++i) {
    int cl = ty + i * 8;
    L[cl][tx] = f2bf(x[((size_t)(n * C + ct * 32 + cl)) * HW + hwt * 32 + tx]);
  }
  __syncthreads();
#pragma unroll
  for (int i = 0; i < 4; ++i) {
    int hl = ty + i * 8;
    int hw = hwt * 32 + hl;
    int y = hw / W_, xx = hw % W_;
    xp[((size_t)n * PHW + (y + 1) * PW + (xx + 1)) * C + ct * 32 + tx] = L[tx][hl];
  }
}

// wB[o][kk*C+c] = bf16(w[o][c][kk])   (B^T layout for MFMA)
__global__ void transpose_w_kernel(const float* __restrict__ w,
                                   ushort_t* __restrict__ wB, int C) {
  int K = C * 9;
  int i = blockIdx.x * 256 + threadIdx.x;
  if (i >= 128 * K) return;
  int o = i / K, r = i % K;
  int kk = r / C, c = r % C;
  wB[i] = f2bf(w[(o * C + c) * 9 + kk]);
}

// wOB[o][kk*C+c] = bf16(off_w[o][c][kk]) for o<27, zeros for o in [27,32)
__global__ void transpose_wo_kernel(const float* __restrict__ ow,
                                    ushort_t* __restrict__ wOB, int C) {
  int K = C * 9;
  int i = blockIdx.x * 256 + threadIdx.x;
  if (i >= 32 * K) return;
  int o = i / K, r = i % K;
  int kk = r / C, c = r % C;
  wOB[i] = (o < 27) ? f2bf(ow[(o * C + c) * 9 + kk]) : (ushort_t)0;
}

// ---------------------------------------------------------------------------
__device__ __forceinline__ void gll16(const ushort_t* g, ushort_t* l) {
  __builtin_amdgcn_global_load_lds((const __attribute__((address_space(1))) void*)g,
                                   (__attribute__((address_space(3))) void*)l, 16, 0, 0);
}
__device__ __forceinline__ int swz(int row) {        // 4-slot involution (BK=32)
  return (row & 3) ^ ((row >> 2) & 3);
}

// Offset-conv GEMM with implicit im2col from padded NHWC.
// A[m][kk*C+c] = xp[n][y+ky][x+kx][c] (zero ring = conv padding).
// Block: 64m x 32o, 4 waves each 16m x 32o.  BK=32.
template <int C>
__global__ __launch_bounds__(256) void gemm_off_kernel(
    const ushort_t* __restrict__ xp, const ushort_t* __restrict__ B,
    const float* __restrict__ ob, float* __restrict__ offt, int n0) {
  constexpr int K = C * 9;
  __shared__ __align__(16) ushort_t As[64 * 32];
  __shared__ __align__(16) ushort_t Bs[32 * 32];
  int tid = threadIdx.x;
  int m0 = blockIdx.x * 64;                  // local m within chunk
  int lane = tid & 63, wid = tid >> 6;
  f32x4 acc[2];
  acc[0] = (f32x4){0.f, 0.f, 0.f, 0.f};
  acc[1] = (f32x4){0.f, 0.f, 0.f, 0.f};
  int srow = tid >> 2, chl = tid & 3, q = lane >> 4;
  // staging row -> pixel (fixed across K loop)
  int mg = m0 + srow;
  int nl = mg / HW, hw = mg % HW;
  int y = hw / W_, x = hw % W_;
  const ushort_t* xn = xp + (size_t)(n0 + nl) * PHW * C;
  int pbase = ((y + 1) * PW + (x + 1)) * C;
  int chg = chl ^ swz(srow);
  for (int kt = 0; kt < K; kt += 32) {
    int kk = kt / C, c0 = kt % C;
    int shift = ((kk / 3 - 1) * PW + (kk % 3 - 1)) * C;
    gll16(xn + pbase + shift + c0 + chg * 8, As + tid * 8);
    if (tid < 128) {
      int row = tid >> 2;
      gll16(B + (size_t)row * K + kt + ((tid & 3) ^ swz(row)) * 8, Bs + tid * 8);
    }
    __syncthreads();
    int r = wid * 16 + (lane & 15);
    bf16x8 af = *reinterpret_cast<const bf16x8*>(&As[r * 32 + ((q ^ swz(r)) << 3)]);
#pragma unroll
    for (int oi = 0; oi < 2; ++oi) {
      int rb = oi * 16 + (lane & 15);
      bf16x8 bfr = *reinterpret_cast<const bf16x8*>(&Bs[rb * 32 + ((q ^ swz(rb)) << 3)]);
      acc[oi] = __builtin_amdgcn_mfma_f32_16x16x32_bf16(af, bfr, acc[oi], 0, 0, 0);
    }
    __syncthreads();
  }
#pragma unroll
  for (int oi = 0; oi < 2; ++oi) {
    int o = oi * 16 + (lane & 15);
    if (o < 27) {
      float b = ob[o];
      int mb = n0 * HW + m0 + wid * 16 + ((lane >> 4) << 2);
#pragma unroll
      for (int j = 0; j < 4; ++j)
        offt[(size_t)(mb + j) * 28 + o] = acc[oi][j] + b;
    }
  }
}

// ---------------------------------------------------------------------------
// Deformable bilinear sampling (padded NHWC) -> s[ml][kk*C+c] (bf16).
// cc-FASTEST mapping: contiguous 1KB/wave stores, contiguous corner reads.
template <int C>
__global__ __launch_bounds__(256) void sample_nhwc_kernel(
    const ushort_t* __restrict__ xp, const float* __restrict__ offt,
    ushort_t* __restrict__ s, int n0) {
  constexpr int CH = C / 8;
  int g = blockIdx.x * 256 + threadIdx.x;   // nspan*HW*9*CH (exact)
  int cc = g % CH;
  int t = g / CH;
  int kk = t % 9;
  int ml = t / 9;
  int nl = ml / HW, hw = ml % HW;
  int h = hw / W_, w = hw % W_;
  const float* op = offt + ((size_t)n0 * HW + ml) * 28;
  float dy = op[2 * kk];
  float dx = op[2 * kk + 1];
  float mo = op[18 + kk];
  float mm = 1.f / (1.f + __expf(-mo));
  float py = dy + (float)(kk / 3 - 1 + h);
  float px = dx + (float)(kk % 3 - 1 + w);
  float fy = floorf(py), fx = floorf(px);
  int y0 = (int)fy, x0 = (int)fx;
  float ly = py - fy, lx = px - fx;
  int y1 = y0 + 1, x1 = x0 + 1;
  bool vy0 = (y0 >= 0) & (y0 < H_), vy1 = (y1 >= 0) & (y1 < H_);
  bool vx0 = (x0 >= 0) & (x0 < W_), vx1 = (x1 >= 0) & (x1 < W_);
  int y0c = min(max(y0, 0), H_ - 1), y1c = min(max(y1, 0), H_ - 1);
  int x0c = min(max(x0, 0), W_ - 1), x1c = min(max(x1, 0), W_ - 1);
  float w00 = (vy0 & vx0) ? (1.f - ly) * (1.f - lx) * mm : 0.f;
  float w01 = (vy0 & vx1) ? (1.f - ly) * lx * mm : 0.f;
  float w10 = (vy1 & vx0) ? ly * (1.f - lx) * mm : 0.f;
  float w11 = (vy1 & vx1) ? ly * lx * mm : 0.f;
  const ushort_t* xb = xp + (size_t)(n0 + nl) * PHW * C + cc * 8;
  const ushort_t* p00 = xb + (size_t)((y0c + 1) * PW + x0c + 1) * C;
  const ushort_t* p01 = xb + (size_t)((y0c + 1) * PW + x1c + 1) * C;
  const ushort_t* p10 = xb + (size_t)((y1c + 1) * PW + x0c + 1) * C;
  const ushort_t* p11 = xb + (size_t)((y1c + 1) * PW + x1c + 1) * C;
  u16x8 a = *reinterpret_cast<const u16x8*>(p00);
  u16x8 b = *reinterpret_cast<const u16x8*>(p01);
  u16x8 c2 = *reinterpret_cast<const u16x8*>(p10);
  u16x8 d = *reinterpret_cast<const u16x8*>(p11);
  u16x8 r;
#pragma unroll
  for (int e = 0; e < 8; ++e) {
    float v = w00 * bf2f(a[e]) + w01 * bf2f(b[e])
            + w10 * bf2f(c2[e]) + w11 * bf2f(d[e]);
    r[e] = f2bf(v);
  }
  *reinterpret_cast<u16x8*>(s + ((size_t)ml * 9 + kk) * C + cc * 8) = r;
}

// ---------------------------------------------------------------------------
// Main MFMA GEMM, BK=64: A=s [M][K], B=wB [128][K], Y [M][128] fp32.
// Tile 64m x 128o, 4 waves (2x2), wave 32m x 64o.  8-slot XOR swizzle.
// Fused BN stats: per-channel sum/sumsq atomics from the accumulators.
template <int K>
__global__ __launch_bounds__(256) void gemm_kernel(
    const ushort_t* __restrict__ A, const ushort_t* __restrict__ B,
    float* __restrict__ Y, int mbase, float* __restrict__ stats) {
  __shared__ __align__(16) ushort_t As[64 * 64];    //  8 KB
  __shared__ __align__(16) ushort_t Bs[128 * 64];   // 16 KB
  int tid = threadIdx.x;
  int m0 = blockIdx.x * 64;
  int lane = tid & 63, wid = tid >> 6;
  int wr = wid >> 1, wc = wid & 1;
  f32x4 acc[2][4];
#pragma unroll
  for (int mi = 0; mi < 2; ++mi)
#pragma unroll
    for (int oi = 0; oi < 4; ++oi) acc[mi][oi] = (f32x4){0.f, 0.f, 0.f, 0.f};
  int srow8 = tid >> 3;      // staging row (32 rows/round)
  int slot = tid & 7;        // 8 chunk slots of 8 ushorts
  int q = lane >> 4;
  for (int kt = 0; kt < K; kt += 64) {
    // A: 64 rows x 128B = 2 rounds
#pragma unroll
    for (int rr = 0; rr < 2; ++rr) {
      int row = rr * 32 + srow8;
      gll16(A + (size_t)(m0 + row) * K + kt + ((slot ^ (row & 7)) << 3),
            As + (rr * 256 + tid) * 8);
    }
    // B: 128 rows x 128B = 4 rounds
#pragma unroll
    for (int rr = 0; rr < 4; ++rr) {
      int row = rr * 32 + srow8;
      gll16(B + (size_t)row * K + kt + ((slot ^ (row & 7)) << 3),
            Bs + (rr * 256 + tid) * 8);
    }
    __syncthreads();
    bf16x8 af[2][2], bfr[4][2];
#pragma unroll
    for (int mi = 0; mi < 2; ++mi) {
      int r = wr * 32 + mi * 16 + (lane & 15);
#pragma unroll
      for (int ks = 0; ks < 2; ++ks)
        af[mi][ks] = *reinterpret_cast<const bf16x8*>(
            &As[r * 64 + (((ks * 4 + q) ^ (r & 7)) << 3)]);
    }
#pragma unroll
    for (int oi = 0; oi < 4; ++oi) {
      int r = wc * 64 + oi * 16 + (lane & 15);
#pragma unroll
      for (int ks = 0; ks < 2; ++ks)
        bfr[oi][ks] = *reinterpret_cast<const bf16x8*>(
            &Bs[r * 64 + (((ks * 4 + q) ^ (r & 7)) << 3)]);
    }
#pragma unroll
    for (int ks = 0; ks < 2; ++ks)
#pragma unroll
      for (int mi = 0; mi < 2; ++mi)
#pragma unroll
        for (int oi = 0; oi < 4; ++oi)
          acc[mi][oi] = __builtin_amdgcn_mfma_f32_16x16x32_bf16(
              af[mi][ks], bfr[oi][ks], acc[mi][oi], 0, 0, 0);
    __syncthreads();
  }
  // C-write
#pragma unroll
  for (int mi = 0; mi < 2; ++mi)
#pragma unroll
    for (int oi = 0; oi < 4; ++oi) {
      int o = wc * 64 + oi * 16 + (lane & 15);
      int mb = m0 + wr * 32 + mi * 16 + ((lane >> 4) << 2);
#pragma unroll
      for (int j = 0; j < 4; ++j)
        Y[(size_t)(mbase + mb + j) * O_ + o] = acc[mi][oi][j];
    }
  // fused BN stats: sum/sumsq per channel over this wave's 32 rows
#pragma unroll
  for (int oi = 0; oi < 4; ++oi) {
    float s = 0.f, s2 = 0.f;
#pragma unroll
    for (int mi = 0; mi < 2; ++mi)
#pragma unroll
      for (int j = 0; j < 4; ++j) {
        float v = acc[mi][oi][j];
        s += v; s2 += v * v;
      }
    s  += __shfl_xor(s, 16);  s  += __shfl_xor(s, 32);
    s2 += __shfl_xor(s2, 16); s2 += __shfl_xor(s2, 32);
    if ((lane >> 4) == 0) {
      int o = wc * 64 + oi * 16 + (lane & 15);
      atomicAdd(&stats[o], s);
      atomicAdd(&stats[128 + o], s2);
    }
  }
}

// ---------------------------------------------------------------------------
// BN+ReLU elementwise, Y[m][o] fp32 -> padded NHWC bf16 hp (interior)
__global__ __launch_bounds__(256) void bn_apply_pad_kernel(
    const float* __restrict__ Y, const float* __restrict__ stats,
    const float* __restrict__ gamma, const float* __restrict__ beta,
    ushort_t* __restrict__ hp) {
  int g = blockIdx.x * 256 + threadIdx.x;    // NHW*16
  int m = g >> 4;
  int o0 = (g & 15) * 8;
  int n = m / HW, hw = m % HW;
  int y = hw / W_, x = hw % W_;
  const float4* yp = reinterpret_cast<const float4*>(Y) + (size_t)g * 2;
  float4 a = yp[0], b = yp[1];
  float va[8] = {a.x, a.y, a.z, a.w, b.x, b.y, b.z, b.w};
  u16x8 r;
#pragma unroll
  for (int e = 0; e < 8; ++e) {
    int o = o0 + e;
    float mu = stats[o] * (1.f / (float)NHW);
    float var = stats[128 + o] * (1.f / (float)NHW) - mu * mu;
    float sc = rsqrtf(var + 1e-5f) * gamma[o];
    float sh = beta[o] - mu * sc;
    r[e] = f2bf(fmaxf(fmaf(va[e], sc, sh), 0.f));
  }
  size_t pp = ((size_t)n * PHW + (y + 1) * PW + (x + 1)) * 128;
  *reinterpret_cast<u16x8*>(hp + pp + o0) = r;
}

// BN apply + ReLU, transposing [m][o] -> [n][o][hw] fp32 (final output)
__global__ __launch_bounds__(256) void bn_apply_t_kernel(
    const float* __restrict__ Y, const float* __restrict__ stats,
    const float* __restrict__ gamma, const float* __restrict__ beta,
    float* __restrict__ outf) {
  __shared__ float L[64][129];
  __shared__ float Lsc[128], Lsh[128];
  int tid = threadIdx.x;
  int m0 = blockIdx.x * 64;
  if (tid < 128) {
    float mu = stats[tid] * (1.f / (float)NHW);
    float var = stats[128 + tid] * (1.f / (float)NHW) - mu * mu;
    float sc = rsqrtf(var + 1e-5f) * gamma[tid];
    Lsc[tid] = sc;
    Lsh[tid] = beta[tid] - mu * sc;
  }
#pragma unroll
  for (int it = 0; it < 8; ++it) {
    int idx = it * 256 + tid;
    int ml = idx >> 5, oq = idx & 31;
    float4 v = *reinterpret_cast<const float4*>(&Y[(size_t)(m0 + ml) * O_ + oq * 4]);
    L[ml][oq * 4 + 0] = v.x; L[ml][oq * 4 + 1] = v.y;
    L[ml][oq * 4 + 2] = v.z; L[ml][oq * 4 + 3] = v.w;
  }
  __syncthreads();
  int n = m0 / HW, hw0 = m0 % HW;
#pragma unroll
  for (int it = 0; it < 32; ++it) {
    int idx = it * 256 + tid;
    int ol = idx >> 6, ml = idx & 63;
    float r = fmaxf(fmaf(L[ml][ol], Lsc[ol], Lsh[ol]), 0.f);
    outf[((size_t)n * O_ + ol) * HW + hw0 + ml] = r;
  }
}

// ---------------------------------------------------------------------------
extern "C" void kernel_launch(void* const* d_in, const int* in_sizes, int n_in,
                              void* d_out, int out_size, void* d_ws, size_t ws_size,
                              hipStream_t stream) {
  const float* x      = (const float*)d_in[0];
  const float* w1     = (const float*)d_in[1];
  const float* off_w1 = (const float*)d_in[2];
  const float* off_b1 = (const float*)d_in[3];
  const float* gamma1 = (const float*)d_in[4];
  const float* beta1  = (const float*)d_in[5];
  const float* w2     = (const float*)d_in[6];
  const float* off_w2 = (const float*)d_in[7];
  const float* off_b2 = (const float*)d_in[8];
  const float* gamma2 = (const float*)d_in[9];
  const float* beta2  = (const float*)d_in[10];
  float* out = (float*)d_out;

  char* p = (char*)d_ws;
  auto alloc = [&](size_t bytes) -> void* {
    void* r = (void*)p;
    p += (bytes + 255) & ~(size_t)255;
    return r;
  };
  float*    offt  = (float*)alloc((size_t)NHW * 28 * 4);            // 4.13 MB
  float*    Y     = (float*)alloc((size_t)NHW * O_ * 4);            // 18.9 MB
  float*    stats = (float*)alloc(512 * 4);
  ushort_t* wB1   = (ushort_t*)alloc(73728 * 2);
  ushort_t* wB2   = (ushort_t*)alloc(147456 * 2);
  ushort_t* wOB1  = (ushort_t*)alloc(32 * 576 * 2);
  ushort_t* wOB2  = (ushort_t*)alloc(32 * 1152 * 2);
  ushort_t* xp    = (ushort_t*)alloc((size_t)N_ * PHW * 64 * 2);    // 4.92 MB
  ushort_t* hp    = (ushort_t*)alloc((size_t)N_ * PHW * 128 * 2);   // 9.84 MB
  size_t used = (size_t)(p - (char*)d_ws);
  size_t s_full = (size_t)NHW * 1152 * 2;                           // 84.9 MB
  int nspan = (ws_size >= used + s_full) ? 4 : 1;                   // chunk if tight
  ushort_t* sbuf = (ushort_t*)p;

  // prep: zero padded buffers (xp,hp contiguous -> one fill) + stats
  hipMemsetAsync(xp, 0, (size_t)N_ * PHW * (64 + 128) * 2, stream);
  hipMemsetAsync(stats, 0, 512 * 4, stream);
  to_nhwc_pad_kernel<<<2304, 256, 0, stream>>>(x, xp, 64);
  transpose_w_kernel<<<288, 256, 0, stream>>>(w1, wB1, 64);
  transpose_w_kernel<<<576, 256, 0, stream>>>(w2, wB2, 128);
  transpose_wo_kernel<<<72, 256, 0, stream>>>(off_w1, wOB1, 64);
  transpose_wo_kernel<<<144, 256, 0, stream>>>(off_w2, wOB2, 128);

  // ---- layer 1 (C=64, K=576) ----
  for (int n0 = 0; n0 < 4; n0 += nspan) {
    gemm_off_kernel<64><<<nspan * 144, 256, 0, stream>>>(xp, wOB1, off_b1, offt, n0);
    sample_nhwc_kernel<64><<<nspan * 2592, 256, 0, stream>>>(xp, offt, sbuf, n0);
    gemm_kernel<576><<<nspan * 144, 256, 0, stream>>>(sbuf, wB1, Y, n0 * HW, stats);
  }
  bn_apply_pad_kernel<<<2304, 256, 0, stream>>>(Y, stats, gamma1, beta1, hp);

  // ---- layer 2 (C=128, K=1152) ----
  for (int n0 = 0; n0 < 4; n0 += nspan) {
    gemm_off_kernel<128><<<nspan * 144, 256, 0, stream>>>(hp, wOB2, off_b2, offt, n0);
    sample_nhwc_kernel<128><<<nspan * 5184, 256, 0, stream>>>(hp, offt, sbuf, n0);
    gemm_kernel<1152><<<nspan * 144, 256, 0, stream>>>(sbuf, wB2, Y, n0 * HW, stats + 256);
  }
  bn_apply_t_kernel<<<576, 256, 0, stream>>>(Y, stats + 256, gamma2, beta2, out);
}

// Round 12
// 258.371 us; speedup vs baseline: 1.0460x; 1.0460x over previous
//
#include <hip/hip_runtime.h>
#include <math.h>

#define N_  4
#define H_  96
#define W_  96
#define HW  9216          // H*W
#define NHW 36864         // N*H*W
#define O_  128
#define PW  98            // padded width/height
#define PHW 9604          // PW*PW

typedef unsigned short ushort_t;
typedef __attribute__((ext_vector_type(8))) short bf16x8;
typedef __attribute__((ext_vector_type(4))) float f32x4;
typedef __attribute__((ext_vector_type(8))) unsigned short u16x8;

__device__ __forceinline__ float bf2f(ushort_t u) {
  return __uint_as_float(((unsigned int)u) << 16);
}
__device__ __forceinline__ ushort_t f2bf(float f) {
  unsigned int u = __float_as_uint(f);
  u += 0x7fffu + ((u >> 16) & 1u);           // RNE
  return (ushort_t)(u >> 16);
}

// ---------------------------------------------------------------------------
// NCHW fp32 -> padded NHWC bf16 ([n][98][98][C], interior only; borders memset)
__global__ __launch_bounds__(256) void to_nhwc_pad_kernel(const float* __restrict__ x,
                                                          ushort_t* __restrict__ xp, int C) {
  __shared__ ushort_t L[32][33];
  int ctiles = C >> 5;
  int b = blockIdx.x;
  int ct = b % ctiles;
  int hwt = (b / ctiles) % (HW / 32);
  int n = b / (ctiles * (HW / 32));
  int tx = threadIdx.x & 31, ty = threadIdx.x >> 5;
#pragma unroll
  for (int i = 0; i < 4; ++i) {
    int cl = ty + i * 8;
    L[cl][tx] = f2bf(x[((size_t)(n * C + ct * 32 + cl)) * HW + hwt * 32 + tx]);
  }
  __syncthreads();
#pragma unroll
  for (int i = 0; i < 4; ++i) {
    int hl = ty + i * 8;
    int hw = hwt * 32 + hl;
    int y = hw / W_, xx = hw % W_;
    xp[((size_t)n * PHW + (y + 1) * PW + (xx + 1)) * C + ct * 32 + tx] = L[tx][hl];
  }
}

// wB[o][kk*C+c] = bf16(w[o][c][kk])   (B^T layout for MFMA)
__global__ void transpose_w_kernel(const float* __restrict__ w,
                                   ushort_t* __restrict__ wB, int C) {
  int K = C * 9;
  int i = blockIdx.x * 256 + threadIdx.x;
  if (i >= 128 * K) return;
  int o = i / K, r = i % K;
  int kk = r / C, c = r % C;
  wB[i] = f2bf(w[(o * C + c) * 9 + kk]);
}

// wOB[o][kk*C+c] = bf16(off_w[o][c][kk]) for o<27, zeros for o in [27,32)
__global__ void transpose_wo_kernel(const float* __restrict__ ow,
                                    ushort_t* __restrict__ wOB, int C) {
  int K = C * 9;
  int i = blockIdx.x * 256 + threadIdx.x;
  if (i >= 32 * K) return;
  int o = i / K, r = i % K;
  int kk = r / C, c = r % C;
  wOB[i] = (o < 27) ? f2bf(ow[(o * C + c) * 9 + kk]) : (ushort_t)0;
}

// ---------------------------------------------------------------------------
__device__ __forceinline__ void gll16(const ushort_t* g, ushort_t* l) {
  __builtin_amdgcn_global_load_lds((const __attribute__((address_space(1))) void*)g,
                                   (__attribute__((address_space(3))) void*)l, 16, 0, 0);
}
__device__ __forceinline__ int swz(int row) {        // 4-slot involution (BK=32)
  return (row & 3) ^ ((row >> 2) & 3);
}

// Offset-conv GEMM with implicit im2col from padded NHWC.
// A[m][kk*C+c] = xp[n][y+ky][x+kx][c] (zero ring = conv padding).
// Block: 64m x 32o, 4 waves each 16m x 32o.  BK=32.
template <int C>
__global__ __launch_bounds__(256) void gemm_off_kernel(
    const ushort_t* __restrict__ xp, const ushort_t* __restrict__ B,
    const float* __restrict__ ob, float* __restrict__ offt) {
  constexpr int K = C * 9;
  __shared__ __align__(16) ushort_t As[64 * 32];
  __shared__ __align__(16) ushort_t Bs[32 * 32];
  int tid = threadIdx.x;
  int m0 = blockIdx.x * 64;
  int lane = tid & 63, wid = tid >> 6;
  f32x4 acc[2];
  acc[0] = (f32x4){0.f, 0.f, 0.f, 0.f};
  acc[1] = (f32x4){0.f, 0.f, 0.f, 0.f};
  int srow = tid >> 2, chl = tid & 3, q = lane >> 4;
  int mg = m0 + srow;
  int nl = mg / HW, hw = mg % HW;
  int y = hw / W_, x = hw % W_;
  const ushort_t* xn = xp + (size_t)nl * PHW * C;
  int pbase = ((y + 1) * PW + (x + 1)) * C;
  int chg = chl ^ swz(srow);
  for (int kt = 0; kt < K; kt += 32) {
    int kk = kt / C, c0 = kt % C;
    int shift = ((kk / 3 - 1) * PW + (kk % 3 - 1)) * C;
    gll16(xn + pbase + shift + c0 + chg * 8, As + tid * 8);
    if (tid < 128) {
      int row = tid >> 2;
      gll16(B + (size_t)row * K + kt + ((tid & 3) ^ swz(row)) * 8, Bs + tid * 8);
    }
    __syncthreads();
    int r = wid * 16 + (lane & 15);
    bf16x8 af = *reinterpret_cast<const bf16x8*>(&As[r * 32 + ((q ^ swz(r)) << 3)]);
#pragma unroll
    for (int oi = 0; oi < 2; ++oi) {
      int rb = oi * 16 + (lane & 15);
      bf16x8 bfr = *reinterpret_cast<const bf16x8*>(&Bs[rb * 32 + ((q ^ swz(rb)) << 3)]);
      acc[oi] = __builtin_amdgcn_mfma_f32_16x16x32_bf16(af, bfr, acc[oi], 0, 0, 0);
    }
    __syncthreads();
  }
#pragma unroll
  for (int oi = 0; oi < 2; ++oi) {
    int o = oi * 16 + (lane & 15);
    if (o < 27) {
      float b = ob[o];
      int mb = m0 + wid * 16 + ((lane >> 4) << 2);
#pragma unroll
      for (int j = 0; j < 4; ++j)
        offt[(size_t)(mb + j) * 28 + o] = acc[oi][j] + b;
    }
  }
}

// ---------------------------------------------------------------------------
// FUSED deformable-sample + MFMA GEMM (no materialized A).
// Each thread stages its (row, 8ch) A-fragment: 4 contiguous u16x8 corner
// loads from padded NHWC -> bilinear blend in regs -> ds_write to swizzled
// LDS slot. Per-tap meta recomputed in regs when kt%C==0.
// Tile 64m x 128o, 4 waves (2x2), BK=32.  Fused BN-stats epilogue.
template <int C>
__global__ __launch_bounds__(256) void gemm_fused_kernel(
    const ushort_t* __restrict__ xp, const float* __restrict__ offt,
    const ushort_t* __restrict__ B, float* __restrict__ Y,
    float* __restrict__ stats) {
  constexpr int K = C * 9;
  __shared__ __align__(16) ushort_t As[64 * 32];    // 4 KB
  __shared__ __align__(16) ushort_t Bs[128 * 32];   // 8 KB
  int tid = threadIdx.x;
  int m0 = blockIdx.x * 64;
  int lane = tid & 63, wid = tid >> 6;
  int wr = wid >> 1, wc = wid & 1;
  f32x4 acc[2][4];
#pragma unroll
  for (int mi = 0; mi < 2; ++mi)
#pragma unroll
    for (int oi = 0; oi < 4; ++oi) acc[mi][oi] = (f32x4){0.f, 0.f, 0.f, 0.f};
  int srow = tid >> 2, chl = tid & 3, q = lane >> 4;
  int mg = m0 + srow;
  int n = mg / HW, hw = mg % HW;
  int h = hw / W_, w = hw % W_;
  const float* op = offt + (size_t)mg * 28;
  const ushort_t* xb = xp + (size_t)n * PHW * C;
  const ushort_t *p00 = xb, *p01 = xb, *p10 = xb, *p11 = xb;
  float w00 = 0.f, w01 = 0.f, w10 = 0.f, w11 = 0.f;
  int wslot = (chl ^ swz(srow)) << 3;

  for (int kt = 0; kt < K; kt += 32) {
    int kk = kt / C, c0 = kt % C;
    if (c0 == 0) {   // tap changed: recompute bilinear meta in registers
      float dy = op[2 * kk], dx = op[2 * kk + 1], mo = op[18 + kk];
      float mm = 1.f / (1.f + __expf(-mo));
      float py = dy + (float)(kk / 3 - 1 + h);
      float px = dx + (float)(kk % 3 - 1 + w);
      float fy = floorf(py), fx = floorf(px);
      int y0 = (int)fy, x0 = (int)fx;
      float ly = py - fy, lx = px - fx;
      int y1 = y0 + 1, x1 = x0 + 1;
      bool vy0 = (y0 >= 0) & (y0 < H_), vy1 = (y1 >= 0) & (y1 < H_);
      bool vx0 = (x0 >= 0) & (x0 < W_), vx1 = (x1 >= 0) & (x1 < W_);
      int y0c = min(max(y0, 0), H_ - 1), y1c = min(max(y1, 0), H_ - 1);
      int x0c = min(max(x0, 0), W_ - 1), x1c = min(max(x1, 0), W_ - 1);
      w00 = (vy0 & vx0) ? (1.f - ly) * (1.f - lx) * mm : 0.f;
      w01 = (vy0 & vx1) ? (1.f - ly) * lx * mm : 0.f;
      w10 = (vy1 & vx0) ? ly * (1.f - lx) * mm : 0.f;
      w11 = (vy1 & vx1) ? ly * lx * mm : 0.f;
      p00 = xb + (size_t)((y0c + 1) * PW + x0c + 1) * C;
      p01 = xb + (size_t)((y0c + 1) * PW + x1c + 1) * C;
      p10 = xb + (size_t)((y1c + 1) * PW + x0c + 1) * C;
      p11 = xb + (size_t)((y1c + 1) * PW + x1c + 1) * C;
    }
    // B staging via global_load_lds (2 rounds, 128 rows x 64B)
#pragma unroll
    for (int rr = 0; rr < 2; ++rr) {
      int row = srow + 64 * rr;
      gll16(B + (size_t)row * K + kt + ((chl ^ swz(row)) << 3), Bs + rr * 2048 + tid * 8);
    }
    // A staging: sample 8 channels in registers
    int c = c0 + chl * 8;
    u16x8 va = *reinterpret_cast<const u16x8*>(p00 + c);
    u16x8 vb = *reinterpret_cast<const u16x8*>(p01 + c);
    u16x8 vc = *reinterpret_cast<const u16x8*>(p10 + c);
    u16x8 vd = *reinterpret_cast<const u16x8*>(p11 + c);
    u16x8 r;
#pragma unroll
    for (int e = 0; e < 8; ++e) {
      float v = w00 * bf2f(va[e]) + w01 * bf2f(vb[e])
              + w10 * bf2f(vc[e]) + w11 * bf2f(vd[e]);
      r[e] = f2bf(v);
    }
    *reinterpret_cast<u16x8*>(&As[srow * 32 + wslot]) = r;
    __syncthreads();
    bf16x8 af[2], bfr[4];
#pragma unroll
    for (int mi = 0; mi < 2; ++mi) {
      int rr2 = wr * 32 + mi * 16 + (lane & 15);
      af[mi] = *reinterpret_cast<const bf16x8*>(&As[rr2 * 32 + ((q ^ swz(rr2)) << 3)]);
    }
#pragma unroll
    for (int oi = 0; oi < 4; ++oi) {
      int rr2 = wc * 64 + oi * 16 + (lane & 15);
      bfr[oi] = *reinterpret_cast<const bf16x8*>(&Bs[rr2 * 32 + ((q ^ swz(rr2)) << 3)]);
    }
#pragma unroll
    for (int mi = 0; mi < 2; ++mi)
#pragma unroll
      for (int oi = 0; oi < 4; ++oi)
        acc[mi][oi] = __builtin_amdgcn_mfma_f32_16x16x32_bf16(af[mi], bfr[oi], acc[mi][oi], 0, 0, 0);
    __syncthreads();
  }
  // C-write
#pragma unroll
  for (int mi = 0; mi < 2; ++mi)
#pragma unroll
    for (int oi = 0; oi < 4; ++oi) {
      int o = wc * 64 + oi * 16 + (lane & 15);
      int mb = m0 + wr * 32 + mi * 16 + ((lane >> 4) << 2);
#pragma unroll
      for (int j = 0; j < 4; ++j)
        Y[(size_t)(mb + j) * O_ + o] = acc[mi][oi][j];
    }
  // fused BN stats: per-channel sum/sumsq over this wave's 32 rows
#pragma unroll
  for (int oi = 0; oi < 4; ++oi) {
    float s = 0.f, s2 = 0.f;
#pragma unroll
    for (int mi = 0; mi < 2; ++mi)
#pragma unroll
      for (int j = 0; j < 4; ++j) {
        float v = acc[mi][oi][j];
        s += v; s2 += v * v;
      }
    s  += __shfl_xor(s, 16);  s  += __shfl_xor(s, 32);
    s2 += __shfl_xor(s2, 16); s2 += __shfl_xor(s2, 32);
    if ((lane >> 4) == 0) {
      int o = wc * 64 + oi * 16 + (lane & 15);
      atomicAdd(&stats[o], s);
      atomicAdd(&stats[128 + o], s2);
    }
  }
}

// ---------------------------------------------------------------------------
// BN+ReLU elementwise, Y[m][o] fp32 -> padded NHWC bf16 hp (interior)
__global__ __launch_bounds__(256) void bn_apply_pad_kernel(
    const float* __restrict__ Y, const float* __restrict__ stats,
    const float* __restrict__ gamma, const float* __restrict__ beta,
    ushort_t* __restrict__ hp) {
  int g = blockIdx.x * 256 + threadIdx.x;    // NHW*16
  int m = g >> 4;
  int o0 = (g & 15) * 8;
  int n = m / HW, hw = m % HW;
  int y = hw / W_, x = hw % W_;
  const float4* yp = reinterpret_cast<const float4*>(Y) + (size_t)g * 2;
  float4 a = yp[0], b = yp[1];
  float va[8] = {a.x, a.y, a.z, a.w, b.x, b.y, b.z, b.w};
  u16x8 r;
#pragma unroll
  for (int e = 0; e < 8; ++e) {
    int o = o0 + e;
    float mu = stats[o] * (1.f / (float)NHW);
    float var = stats[128 + o] * (1.f / (float)NHW) - mu * mu;
    float sc = rsqrtf(var + 1e-5f) * gamma[o];
    float sh = beta[o] - mu * sc;
    r[e] = f2bf(fmaxf(fmaf(va[e], sc, sh), 0.f));
  }
  size_t pp = ((size_t)n * PHW + (y + 1) * PW + (x + 1)) * 128;
  *reinterpret_cast<u16x8*>(hp + pp + o0) = r;
}

// BN apply + ReLU, transposing [m][o] -> [n][o][hw] fp32 (final output)
__global__ __launch_bounds__(256) void bn_apply_t_kernel(
    const float* __restrict__ Y, const float* __restrict__ stats,
    const float* __restrict__ gamma, const float* __restrict__ beta,
    float* __restrict__ outf) {
  __shared__ float L[64][129];
  __shared__ float Lsc[128], Lsh[128];
  int tid = threadIdx.x;
  int m0 = blockIdx.x * 64;
  if (tid < 128) {
    float mu = stats[tid] * (1.f / (float)NHW);
    float var = stats[128 + tid] * (1.f / (float)NHW) - mu * mu;
    float sc = rsqrtf(var + 1e-5f) * gamma[tid];
    Lsc[tid] = sc;
    Lsh[tid] = beta[tid] - mu * sc;
  }
#pragma unroll
  for (int it = 0; it < 8; ++it) {
    int idx = it * 256 + tid;
    int ml = idx >> 5, oq = idx & 31;
    float4 v = *reinterpret_cast<const float4*>(&Y[(size_t)(m0 + ml) * O_ + oq * 4]);
    L[ml][oq * 4 + 0] = v.x; L[ml][oq * 4 + 1] = v.y;
    L[ml][oq * 4 + 2] = v.z; L[ml][oq * 4 + 3] = v.w;
  }
  __syncthreads();
  int n = m0 / HW, hw0 = m0 % HW;
#pragma unroll
  for (int it = 0; it < 32; ++it) {
    int idx = it * 256 + tid;
    int ol = idx >> 6, ml = idx & 63;
    float r = fmaxf(fmaf(L[ml][ol], Lsc[ol], Lsh[ol]), 0.f);
    outf[((size_t)n * O_ + ol) * HW + hw0 + ml] = r;
  }
}

// ---------------------------------------------------------------------------
extern "C" void kernel_launch(void* const* d_in, const int* in_sizes, int n_in,
                              void* d_out, int out_size, void* d_ws, size_t ws_size,
                              hipStream_t stream) {
  const float* x      = (const float*)d_in[0];
  const float* w1     = (const float*)d_in[1];
  const float* off_w1 = (const float*)d_in[2];
  const float* off_b1 = (const float*)d_in[3];
  const float* gamma1 = (const float*)d_in[4];
  const float* beta1  = (const float*)d_in[5];
  const float* w2     = (const float*)d_in[6];
  const float* off_w2 = (const float*)d_in[7];
  const float* off_b2 = (const float*)d_in[8];
  const float* gamma2 = (const float*)d_in[9];
  const float* beta2  = (const float*)d_in[10];
  float* out = (float*)d_out;

  char* p = (char*)d_ws;
  auto alloc = [&](size_t bytes) -> void* {
    void* r = (void*)p;
    p += (bytes + 255) & ~(size_t)255;
    return r;
  };
  float*    offt  = (float*)alloc((size_t)NHW * 28 * 4);            // 4.13 MB
  float*    Y     = (float*)alloc((size_t)NHW * O_ * 4);            // 18.9 MB
  float*    stats = (float*)alloc(512 * 4);
  ushort_t* wB1   = (ushort_t*)alloc(73728 * 2);
  ushort_t* wB2   = (ushort_t*)alloc(147456 * 2);
  ushort_t* wOB1  = (ushort_t*)alloc(32 * 576 * 2);
  ushort_t* wOB2  = (ushort_t*)alloc(32 * 1152 * 2);
  ushort_t* xp    = (ushort_t*)alloc((size_t)N_ * PHW * 64 * 2);    // 4.92 MB
  ushort_t* hp    = (ushort_t*)alloc((size_t)N_ * PHW * 128 * 2);   // 9.84 MB

  // prep: zero padded buffers (xp,hp contiguous -> one fill) + stats
  hipMemsetAsync(xp, 0, (size_t)N_ * PHW * (64 + 128) * 2, stream);
  hipMemsetAsync(stats, 0, 512 * 4, stream);
  to_nhwc_pad_kernel<<<2304, 256, 0, stream>>>(x, xp, 64);
  transpose_w_kernel<<<288, 256, 0, stream>>>(w1, wB1, 64);
  transpose_w_kernel<<<576, 256, 0, stream>>>(w2, wB2, 128);
  transpose_wo_kernel<<<72, 256, 0, stream>>>(off_w1, wOB1, 64);
  transpose_wo_kernel<<<144, 256, 0, stream>>>(off_w2, wOB2, 128);

  // ---- layer 1 (C=64, K=576) ----
  gemm_off_kernel<64><<<576, 256, 0, stream>>>(xp, wOB1, off_b1, offt);
  gemm_fused_kernel<64><<<576, 256, 0, stream>>>(xp, offt, wB1, Y, stats);
  bn_apply_pad_kernel<<<2304, 256, 0, stream>>>(Y, stats, gamma1, beta1, hp);

  // ---- layer 2 (C=128, K=1152) ----
  gemm_off_kernel<128><<<576, 256, 0, stream>>>(hp, wOB2, off_b2, offt);
  gemm_fused_kernel<128><<<576, 256, 0, stream>>>(hp, offt, wB2, Y, stats + 256);
  bn_apply_t_kernel<<<576, 256, 0, stream>>>(Y, stats + 256, gamma2, beta2, out);
}

// Round 13
// 250.411 us; speedup vs baseline: 1.0793x; 1.0318x over previous
//
#include <hip/hip_runtime.h>
#include <math.h>

#define N_  4
#define H_  96
#define W_  96
#define HW  9216          // H*W
#define NHW 36864         // N*H*W
#define O_  128
#define PW  98            // padded width/height
#define PHW 9604          // PW*PW

typedef unsigned short ushort_t;
typedef __attribute__((ext_vector_type(8))) short bf16x8;
typedef __attribute__((ext_vector_type(4))) float f32x4;
typedef __attribute__((ext_vector_type(8))) unsigned short u16x8;

__device__ __forceinline__ float bf2f(ushort_t u) {
  return __uint_as_float(((unsigned int)u) << 16);
}
__device__ __forceinline__ ushort_t f2bf(float f) {
  unsigned int u = __float_as_uint(f);
  u += 0x7fffu + ((u >> 16) & 1u);           // RNE
  return (ushort_t)(u >> 16);
}

// ---------------------------------------------------------------------------
// NCHW fp32 -> padded NHWC bf16 ([n][98][98][C], interior only; borders memset)
__global__ __launch_bounds__(256) void to_nhwc_pad_kernel(const float* __restrict__ x,
                                                          ushort_t* __restrict__ xp, int C) {
  __shared__ ushort_t L[32][33];
  int ctiles = C >> 5;
  int b = blockIdx.x;
  int ct = b % ctiles;
  int hwt = (b / ctiles) % (HW / 32);
  int n = b / (ctiles * (HW / 32));
  int tx = threadIdx.x & 31, ty = threadIdx.x >> 5;
#pragma unroll
  for (int i = 0; i < 4; ++i) {
    int cl = ty + i * 8;
    L[cl][tx] = f2bf(x[((size_t)(n * C + ct * 32 + cl)) * HW + hwt * 32 + tx]);
  }
  __syncthreads();
#pragma unroll
  for (int i = 0; i < 4; ++i) {
    int hl = ty + i * 8;
    int hw = hwt * 32 + hl;
    int y = hw / W_, xx = hw % W_;
    xp[((size_t)n * PHW + (y + 1) * PW + (xx + 1)) * C + ct * 32 + tx] = L[tx][hl];
  }
}

// wB[o][kk*C+c] = bf16(w[o][c][kk])   (B^T layout for MFMA)
__global__ void transpose_w_kernel(const float* __restrict__ w,
                                   ushort_t* __restrict__ wB, int C) {
  int K = C * 9;
  int i = blockIdx.x * 256 + threadIdx.x;
  if (i >= 128 * K) return;
  int o = i / K, r = i % K;
  int kk = r / C, c = r % C;
  wB[i] = f2bf(w[(o * C + c) * 9 + kk]);
}

// wOB[o][kk*C+c] = bf16(off_w[o][c][kk]) for o<27, zeros for o in [27,32)
__global__ void transpose_wo_kernel(const float* __restrict__ ow,
                                    ushort_t* __restrict__ wOB, int C) {
  int K = C * 9;
  int i = blockIdx.x * 256 + threadIdx.x;
  if (i >= 32 * K) return;
  int o = i / K, r = i % K;
  int kk = r / C, c = r % C;
  wOB[i] = (o < 27) ? f2bf(ow[(o * C + c) * 9 + kk]) : (ushort_t)0;
}

// ---------------------------------------------------------------------------
__device__ __forceinline__ void gll16(const ushort_t* g, ushort_t* l) {
  __builtin_amdgcn_global_load_lds((const __attribute__((address_space(1))) void*)g,
                                   (__attribute__((address_space(3))) void*)l, 16, 0, 0);
}
__device__ __forceinline__ int swz(int row) {        // 4-slot involution (BK=32)
  return (row & 3) ^ ((row >> 2) & 3);
}

// Offset-conv GEMM with implicit im2col from padded NHWC.
// A[m][kk*C+c] = xp[n][y+ky][x+kx][c] (zero ring = conv padding).
// Block: 64m x 32o, 4 waves each 16m x 32o.  BK=32.
template <int C>
__global__ __launch_bounds__(256) void gemm_off_kernel(
    const ushort_t* __restrict__ xp, const ushort_t* __restrict__ B,
    const float* __restrict__ ob, float* __restrict__ offt) {
  constexpr int K = C * 9;
  __shared__ __align__(16) ushort_t As[64 * 32];
  __shared__ __align__(16) ushort_t Bs[32 * 32];
  int tid = threadIdx.x;
  int m0 = blockIdx.x * 64;
  int lane = tid & 63, wid = tid >> 6;
  f32x4 acc[2];
  acc[0] = (f32x4){0.f, 0.f, 0.f, 0.f};
  acc[1] = (f32x4){0.f, 0.f, 0.f, 0.f};
  int srow = tid >> 2, chl = tid & 3, q = lane >> 4;
  int mg = m0 + srow;
  int nl = mg / HW, hw = mg % HW;
  int y = hw / W_, x = hw % W_;
  const ushort_t* xn = xp + (size_t)nl * PHW * C;
  int pbase = ((y + 1) * PW + (x + 1)) * C;
  int chg = chl ^ swz(srow);
  for (int kt = 0; kt < K; kt += 32) {
    int kk = kt / C, c0 = kt % C;
    int shift = ((kk / 3 - 1) * PW + (kk % 3 - 1)) * C;
    gll16(xn + pbase + shift + c0 + chg * 8, As + tid * 8);
    if (tid < 128) {
      int row = tid >> 2;
      gll16(B + (size_t)row * K + kt + ((tid & 3) ^ swz(row)) * 8, Bs + tid * 8);
    }
    __syncthreads();
    int r = wid * 16 + (lane & 15);
    bf16x8 af = *reinterpret_cast<const bf16x8*>(&As[r * 32 + ((q ^ swz(r)) << 3)]);
#pragma unroll
    for (int oi = 0; oi < 2; ++oi) {
      int rb = oi * 16 + (lane & 15);
      bf16x8 bfr = *reinterpret_cast<const bf16x8*>(&Bs[rb * 32 + ((q ^ swz(rb)) << 3)]);
      acc[oi] = __builtin_amdgcn_mfma_f32_16x16x32_bf16(af, bfr, acc[oi], 0, 0, 0);
    }
    __syncthreads();
  }
#pragma unroll
  for (int oi = 0; oi < 2; ++oi) {
    int o = oi * 16 + (lane & 15);
    if (o < 27) {
      float b = ob[o];
      int mb = m0 + wid * 16 + ((lane >> 4) << 2);
#pragma unroll
      for (int j = 0; j < 4; ++j)
        offt[(size_t)(mb + j) * 28 + o] = acc[oi][j] + b;
    }
  }
}

// ---------------------------------------------------------------------------
// FUSED deformable-sample + MFMA GEMM, 512 threads / 8 waves, BK=64.
// Wave grid 2(m) x 4(o): wave tile 32m x 32o = 2x2 frags x 2 k-slices.
// A-staging: row = tid>>3, chunk = tid&7; sample 8ch in regs -> swizzled
// ds_write.  B via global_load_lds (inverse-swizzled source).
// Fused BN-stats epilogue.
template <int C>
__global__ __launch_bounds__(512) void gemm_fused_kernel(
    const ushort_t* __restrict__ xp, const float* __restrict__ offt,
    const ushort_t* __restrict__ B, float* __restrict__ Y,
    float* __restrict__ stats) {
  constexpr int K = C * 9;
  __shared__ __align__(16) ushort_t As[64 * 64];    //  8 KB
  __shared__ __align__(16) ushort_t Bs[128 * 64];   // 16 KB
  int tid = threadIdx.x;
  int m0 = blockIdx.x * 64;
  int lane = tid & 63, wid = tid >> 6;
  int wr = wid >> 2, wc = wid & 3;                  // 2 x 4 waves
  f32x4 acc[2][2];
#pragma unroll
  for (int mi = 0; mi < 2; ++mi)
#pragma unroll
    for (int oi = 0; oi < 2; ++oi) acc[mi][oi] = (f32x4){0.f, 0.f, 0.f, 0.f};
  int srow = tid >> 3;       // staging row 0..63
  int sl = tid & 7;          // channel chunk 0..7 (8 ch each)
  int q = lane >> 4;
  int mg = m0 + srow;
  int n = mg / HW, hw = mg % HW;
  int h = hw / W_, w = hw % W_;
  const float* op = offt + (size_t)mg * 28;
  const ushort_t* xb = xp + (size_t)n * PHW * C;
  const ushort_t *p00 = xb, *p01 = xb, *p10 = xb, *p11 = xb;
  float w00 = 0.f, w01 = 0.f, w10 = 0.f, w11 = 0.f;
  int wpos = (sl ^ (srow & 7)) << 3;                // physical slot (ushorts)

  for (int kt = 0; kt < K; kt += 64) {
    int kk = kt / C, c0 = kt % C;
    if (c0 == 0) {   // tap boundary: recompute bilinear meta in registers
      float dy = op[2 * kk], dx = op[2 * kk + 1], mo = op[18 + kk];
      float mm = 1.f / (1.f + __expf(-mo));
      float py = dy + (float)(kk / 3 - 1 + h);
      float px = dx + (float)(kk % 3 - 1 + w);
      float fy = floorf(py), fx = floorf(px);
      int y0 = (int)fy, x0 = (int)fx;
      float ly = py - fy, lx = px - fx;
      int y1 = y0 + 1, x1 = x0 + 1;
      bool vy0 = (y0 >= 0) & (y0 < H_), vy1 = (y1 >= 0) & (y1 < H_);
      bool vx0 = (x0 >= 0) & (x0 < W_), vx1 = (x1 >= 0) & (x1 < W_);
      int y0c = min(max(y0, 0), H_ - 1), y1c = min(max(y1, 0), H_ - 1);
      int x0c = min(max(x0, 0), W_ - 1), x1c = min(max(x1, 0), W_ - 1);
      w00 = (vy0 & vx0) ? (1.f - ly) * (1.f - lx) * mm : 0.f;
      w01 = (vy0 & vx1) ? (1.f - ly) * lx * mm : 0.f;
      w10 = (vy1 & vx0) ? ly * (1.f - lx) * mm : 0.f;
      w11 = (vy1 & vx1) ? ly * lx * mm : 0.f;
      p00 = xb + (size_t)((y0c + 1) * PW + x0c + 1) * C;
      p01 = xb + (size_t)((y0c + 1) * PW + x1c + 1) * C;
      p10 = xb + (size_t)((y1c + 1) * PW + x0c + 1) * C;
      p11 = xb + (size_t)((y1c + 1) * PW + x1c + 1) * C;
    }
    // B staging: 128 rows x 128B = 2 rounds x 512 threads x 16B, linear dest
#pragma unroll
    for (int rr = 0; rr < 2; ++rr) {
      int row = rr * 64 + srow;
      gll16(B + (size_t)row * K + kt + ((sl ^ (row & 7)) << 3),
            Bs + (rr * 512 + tid) * 8);
    }
    // A staging: sample this thread's 8 channels in registers
    int c = c0 + sl * 8;
    u16x8 va = *reinterpret_cast<const u16x8*>(p00 + c);
    u16x8 vb = *reinterpret_cast<const u16x8*>(p01 + c);
    u16x8 vc = *reinterpret_cast<const u16x8*>(p10 + c);
    u16x8 vd = *reinterpret_cast<const u16x8*>(p11 + c);
    u16x8 r;
#pragma unroll
    for (int e = 0; e < 8; ++e) {
      float v = w00 * bf2f(va[e]) + w01 * bf2f(vb[e])
              + w10 * bf2f(vc[e]) + w11 * bf2f(vd[e]);
      r[e] = f2bf(v);
    }
    *reinterpret_cast<u16x8*>(&As[srow * 64 + wpos]) = r;
    __syncthreads();
    bf16x8 af[2][2], bfr[2][2];
#pragma unroll
    for (int mi = 0; mi < 2; ++mi) {
      int rA = wr * 32 + mi * 16 + (lane & 15);
#pragma unroll
      for (int ks = 0; ks < 2; ++ks)
        af[mi][ks] = *reinterpret_cast<const bf16x8*>(
            &As[rA * 64 + (((ks * 4 + q) ^ (rA & 7)) << 3)]);
    }
#pragma unroll
    for (int oi = 0; oi < 2; ++oi) {
      int rB = wc * 32 + oi * 16 + (lane & 15);
#pragma unroll
      for (int ks = 0; ks < 2; ++ks)
        bfr[oi][ks] = *reinterpret_cast<const bf16x8*>(
            &Bs[rB * 64 + (((ks * 4 + q) ^ (rB & 7)) << 3)]);
    }
#pragma unroll
    for (int ks = 0; ks < 2; ++ks)
#pragma unroll
      for (int mi = 0; mi < 2; ++mi)
#pragma unroll
        for (int oi = 0; oi < 2; ++oi)
          acc[mi][oi] = __builtin_amdgcn_mfma_f32_16x16x32_bf16(
              af[mi][ks], bfr[oi][ks], acc[mi][oi], 0, 0, 0);
    __syncthreads();
  }
  // C-write
#pragma unroll
  for (int mi = 0; mi < 2; ++mi)
#pragma unroll
    for (int oi = 0; oi < 2; ++oi) {
      int o = wc * 32 + oi * 16 + (lane & 15);
      int mb = m0 + wr * 32 + mi * 16 + ((lane >> 4) << 2);
#pragma unroll
      for (int j = 0; j < 4; ++j)
        Y[(size_t)(mb + j) * O_ + o] = acc[mi][oi][j];
    }
  // fused BN stats: per-channel sum/sumsq over this wave's 32 rows
#pragma unroll
  for (int oi = 0; oi < 2; ++oi) {
    float s = 0.f, s2 = 0.f;
#pragma unroll
    for (int mi = 0; mi < 2; ++mi)
#pragma unroll
      for (int j = 0; j < 4; ++j) {
        float v = acc[mi][oi][j];
        s += v; s2 += v * v;
      }
    s  += __shfl_xor(s, 16);  s  += __shfl_xor(s, 32);
    s2 += __shfl_xor(s2, 16); s2 += __shfl_xor(s2, 32);
    if ((lane >> 4) == 0) {
      int o = wc * 32 + oi * 16 + (lane & 15);
      atomicAdd(&stats[o], s);
      atomicAdd(&stats[128 + o], s2);
    }
  }
}

// ---------------------------------------------------------------------------
// BN+ReLU elementwise, Y[m][o] fp32 -> padded NHWC bf16 hp (interior)
__global__ __launch_bounds__(256) void bn_apply_pad_kernel(
    const float* __restrict__ Y, const float* __restrict__ stats,
    const float* __restrict__ gamma, const float* __restrict__ beta,
    ushort_t* __restrict__ hp) {
  int g = blockIdx.x * 256 + threadIdx.x;    // NHW*16
  int m = g >> 4;
  int o0 = (g & 15) * 8;
  int n = m / HW, hw = m % HW;
  int y = hw / W_, x = hw % W_;
  const float4* yp = reinterpret_cast<const float4*>(Y) + (size_t)g * 2;
  float4 a = yp[0], b = yp[1];
  float va[8] = {a.x, a.y, a.z, a.w, b.x, b.y, b.z, b.w};
  u16x8 r;
#pragma unroll
  for (int e = 0; e < 8; ++e) {
    int o = o0 + e;
    float mu = stats[o] * (1.f / (float)NHW);
    float var = stats[128 + o] * (1.f / (float)NHW) - mu * mu;
    float sc = rsqrtf(var + 1e-5f) * gamma[o];
    float sh = beta[o] - mu * sc;
    r[e] = f2bf(fmaxf(fmaf(va[e], sc, sh), 0.f));
  }
  size_t pp = ((size_t)n * PHW + (y + 1) * PW + (x + 1)) * 128;
  *reinterpret_cast<u16x8*>(hp + pp + o0) = r;
}

// BN apply + ReLU, transposing [m][o] -> [n][o][hw] fp32 (final output)
__global__ __launch_bounds__(256) void bn_apply_t_kernel(
    const float* __restrict__ Y, const float* __restrict__ stats,
    const float* __restrict__ gamma, const float* __restrict__ beta,
    float* __restrict__ outf) {
  __shared__ float L[64][129];
  __shared__ float Lsc[128], Lsh[128];
  int tid = threadIdx.x;
  int m0 = blockIdx.x * 64;
  if (tid < 128) {
    float mu = stats[tid] * (1.f / (float)NHW);
    float var = stats[128 + tid] * (1.f / (float)NHW) - mu * mu;
    float sc = rsqrtf(var + 1e-5f) * gamma[tid];
    Lsc[tid] = sc;
    Lsh[tid] = beta[tid] - mu * sc;
  }
#pragma unroll
  for (int it = 0; it < 8; ++it) {
    int idx = it * 256 + tid;
    int ml = idx >> 5, oq = idx & 31;
    float4 v = *reinterpret_cast<const float4*>(&Y[(size_t)(m0 + ml) * O_ + oq * 4]);
    L[ml][oq * 4 + 0] = v.x; L[ml][oq * 4 + 1] = v.y;
    L[ml][oq * 4 + 2] = v.z; L[ml][oq * 4 + 3] = v.w;
  }
  __syncthreads();
  int n = m0 / HW, hw0 = m0 % HW;
#pragma unroll
  for (int it = 0; it < 32; ++it) {
    int idx = it * 256 + tid;
    int ol = idx >> 6, ml = idx & 63;
    float r = fmaxf(fmaf(L[ml][ol], Lsc[ol], Lsh[ol]), 0.f);
    outf[((size_t)n * O_ + ol) * HW + hw0 + ml] = r;
  }
}

// ---------------------------------------------------------------------------
extern "C" void kernel_launch(void* const* d_in, const int* in_sizes, int n_in,
                              void* d_out, int out_size, void* d_ws, size_t ws_size,
                              hipStream_t stream) {
  const float* x      = (const float*)d_in[0];
  const float* w1     = (const float*)d_in[1];
  const float* off_w1 = (const float*)d_in[2];
  const float* off_b1 = (const float*)d_in[3];
  const float* gamma1 = (const float*)d_in[4];
  const float* beta1  = (const float*)d_in[5];
  const float* w2     = (const float*)d_in[6];
  const float* off_w2 = (const float*)d_in[7];
  const float* off_b2 = (const float*)d_in[8];
  const float* gamma2 = (const float*)d_in[9];
  const float* beta2  = (const float*)d_in[10];
  float* out = (float*)d_out;

  char* p = (char*)d_ws;
  auto alloc = [&](size_t bytes) -> void* {
    void* r = (void*)p;
    p += (bytes + 255) & ~(size_t)255;
    return r;
  };
  float*    offt  = (float*)alloc((size_t)NHW * 28 * 4);            // 4.13 MB
  float*    Y     = (float*)alloc((size_t)NHW * O_ * 4);            // 18.9 MB
  float*    stats = (float*)alloc(512 * 4);
  ushort_t* wB1   = (ushort_t*)alloc(73728 * 2);
  ushort_t* wB2   = (ushort_t*)alloc(147456 * 2);
  ushort_t* wOB1  = (ushort_t*)alloc(32 * 576 * 2);
  ushort_t* wOB2  = (ushort_t*)alloc(32 * 1152 * 2);
  ushort_t* xp    = (ushort_t*)alloc((size_t)N_ * PHW * 64 * 2);    // 4.92 MB
  ushort_t* hp    = (ushort_t*)alloc((size_t)N_ * PHW * 128 * 2);   // 9.84 MB

  // prep: zero padded buffers (xp,hp contiguous -> one fill) + stats
  hipMemsetAsync(xp, 0, (size_t)N_ * PHW * (64 + 128) * 2, stream);
  hipMemsetAsync(stats, 0, 512 * 4, stream);
  to_nhwc_pad_kernel<<<2304, 256, 0, stream>>>(x, xp, 64);
  transpose_w_kernel<<<288, 256, 0, stream>>>(w1, wB1, 64);
  transpose_w_kernel<<<576, 256, 0, stream>>>(w2, wB2, 128);
  transpose_wo_kernel<<<72, 256, 0, stream>>>(off_w1, wOB1, 64);
  transpose_wo_kernel<<<144, 256, 0, stream>>>(off_w2, wOB2, 128);

  // ---- layer 1 (C=64, K=576) ----
  gemm_off_kernel<64><<<576, 256, 0, stream>>>(xp, wOB1, off_b1, offt);
  gemm_fused_kernel<64><<<576, 512, 0, stream>>>(xp, offt, wB1, Y, stats);
  bn_apply_pad_kernel<<<2304, 256, 0, stream>>>(Y, stats, gamma1, beta1, hp);

  // ---- layer 2 (C=128, K=1152) ----
  gemm_off_kernel<128><<<576, 256, 0, stream>>>(hp, wOB2, off_b2, offt);
  gemm_fused_kernel<128><<<576, 512, 0, stream>>>(hp, offt, wB2, Y, stats + 256);
  bn_apply_t_kernel<<<576, 256, 0, stream>>>(Y, stats + 256, gamma2, beta2, out);
}